// Round 3
// baseline (421.361 us; speedup 1.0000x reference)
//
#include <hip/hip_runtime.h>
#include <math.h>

#define B 4
#define N 4096
#define D 256
#define PROJ 64
#define TH_HIDDEN 128
#define K_CAP 255
#define ALPHA 0.2f
#define ROWS_PER_BLOCK 8                         // 2 rows per wave, interleaved
#define BLOCKS_PER_BATCH (N / ROWS_PER_BLOCK)    // 512

// native vector type for nontemporal builtins (HIP_vector_type is rejected)
typedef float floatx4 __attribute__((ext_vector_type(4)));

// Measured A/B ledger (MI355X, this harness):
//   cached 1-row 446.2 | nt 1-row 437.5 | nt 2-row 428.4 | cached 2-row 442.0 |
//   nt 4-row 433.5 | fused+fences 531.4 | R2 prep-parallel 400.5 (BEST)
// nt (L2-bypass) wins for the 268 MB single-use adj stream; 2-row interleave
// is the MLP sweet spot. ~320 µs of dur_us is harness poison-fills (2x160 µs
// 1-GiB fillBuffer inside the timed region) — uncontrollable.
// R3: (a) prep merged into score as a redundant per-block prefix (argmax on
//     the already-staged LDS mask, shfl split-K projections, L2-broadcast
//     weights) — kills 1 dispatch + gap; LDS 19.75 KB keeps 8 blocks/CU.
//     (b) finalize rewritten with wave-shfl scans: ~110 barriers -> ~20.
//     Streaming hot loop byte-identical to the 400.5 config.

// -------------------- kernel 1: streaming adj pass (+ fused prep prefix)
__global__ __launch_bounds__(256) void score_kernel(
    const float* __restrict__ x, const float* __restrict__ adj,
    const float* __restrict__ cluster_mask, const float* __restrict__ cand_mask,
    const float* __restrict__ seed_ctx, const float* __restrict__ local_stats,
    const float* __restrict__ Wq, const float* __restrict__ Wk,
    const float* __restrict__ th_w1, const float* __restrict__ th_b1,
    const float* __restrict__ th_w2, const float* __restrict__ th_b2,
    float* __restrict__ p_ws, float* __restrict__ theta_out)
{
    const int b = blockIdx.x / BLOCKS_PER_BATCH;
    const int chunk = blockIdx.x % BLOCKS_PER_BATCH;
    const int t = threadIdx.x;
    const int wave = t >> 6;
    const int lane = t & 63;

    __shared__ float s_mask[N];     // 16 KB
    __shared__ float s_v[D];        // 1 KB
    __shared__ float s_xh[256];     // phase C/D: x_seed; phase E/F: h (0..127)
    __shared__ float s_mlp[256];    // MLP hidden partials
    __shared__ float s_r[PROJ];
    __shared__ float s_argv[4];
    __shared__ int   s_argi[4];
    __shared__ float s_theta;

    // ---- Phase A: stage cluster_mask (needed by argmax AND the stream loop)
    for (int i = t * 4; i < N; i += 1024)
        *(float4*)&s_mask[i] = *(const float4*)&cluster_mask[b * N + i];
    __syncthreads();

    // ---- Phase B: argmax (first occurrence of max, matching np.argmax)
    {
        float bestv = -1e30f; int besti = 0;
        for (int i = t; i < N; i += 256) {
            float vv = s_mask[i];
            if (vv > bestv) { bestv = vv; besti = i; }   // strict > keeps lowest idx
        }
        for (int off = 32; off; off >>= 1) {
            float v2 = __shfl_down(bestv, off, 64);
            int   i2 = __shfl_down(besti, off, 64);
            if (v2 > bestv || (v2 == bestv && i2 < besti)) { bestv = v2; besti = i2; }
        }
        if (lane == 0) { s_argv[wave] = bestv; s_argi[wave] = besti; }
    }
    __syncthreads();
    if (t == 0) {
        float bv = s_argv[0]; int bi = s_argi[0];
        #pragma unroll
        for (int w = 1; w < 4; ++w) {
            float v2 = s_argv[w]; int i2 = s_argi[w];
            if (v2 > bv || (v2 == bv && i2 < bi)) { bv = v2; bi = i2; }
        }
        s_argi[0] = bi;
    }
    __syncthreads();
    const int seed = s_argi[0];

    // ---- Phase C: stage x[b,seed,:] + MLP hidden partials (independent work)
    s_xh[t] = x[(size_t)b * N * D + (size_t)seed * D + t];
    {
        // split-K: 2 threads per neuron j; weights/inputs L2-broadcast across blocks
        const int j = t & 127;
        const int h = t >> 7;
        const float* w1 = th_w1 + (size_t)(h * 256) * TH_HIDDEN + j;
        float acc = 0.f;
        if (h == 0) {
            const float* sc = seed_ctx + b * 384;
            #pragma unroll 8
            for (int i = 0; i < 256; ++i) acc += sc[i] * w1[i * TH_HIDDEN];
        } else {
            const float* sc = seed_ctx + b * 384 + 256;
            #pragma unroll 8
            for (int i = 0; i < 128; ++i) acc += sc[i] * w1[i * TH_HIDDEN];
            const float* ls = local_stats + b * 128;
            const float* w1b = w1 + 128 * TH_HIDDEN;
            #pragma unroll 8
            for (int i = 0; i < 128; ++i) acc += ls[i] * w1b[i * TH_HIDDEN];
        }
        s_mlp[t] = acc;
    }
    __syncthreads();

    // ---- Phase D: r[j] = Wq^T x_seed, 4 lanes per output (shfl_xor reduce)
    {
        const int j = (wave << 4) + (lane >> 2);   // wave w owns j in [16w,16w+16)
        const int q = lane & 3;                    // K-quarter
        const float* xs = s_xh + q * 64;
        const float* wq = Wq + (size_t)(q * 64) * PROJ + j;
        float acc = 0.f;
        #pragma unroll 8
        for (int d = 0; d < 64; ++d) acc += xs[d] * wq[d * PROJ];
        acc += __shfl_xor(acc, 1, 64);
        acc += __shfl_xor(acc, 2, 64);
        if (q == 0) s_r[j] = acc;
    }
    __syncthreads();

    // ---- Phase E: finish hidden layer (overwrites dead x_seed region)
    if (t < TH_HIDDEN)
        s_xh[t] = fmaxf(s_mlp[t] + s_mlp[t + 128] + th_b1[t], 0.f);
    __syncthreads();

    // ---- Phase F: v[t] = (Wk[t,:] . r)/8 ; wave 1 reduces theta
    {
        const float4* wk = (const float4*)(Wk + (size_t)t * PROJ);
        float acc = 0.f;
        #pragma unroll
        for (int j4 = 0; j4 < PROJ / 4; ++j4) {
            float4 w = wk[j4];
            float4 r4 = *(const float4*)&s_r[j4 * 4];
            acc += w.x * r4.x + w.y * r4.y + w.z * r4.z + w.w * r4.w;
        }
        s_v[t] = acc * 0.125f;
    }
    if (wave == 1) {
        float a2 = s_xh[lane] * th_w2[lane] + s_xh[lane + 64] * th_w2[lane + 64];
        for (int off = 32; off; off >>= 1) a2 += __shfl_down(a2, off, 64);
        if (lane == 0) s_theta = a2 + th_b2[0];
    }
    __syncthreads();

    // one designated block per batch exports theta (the actual output slot)
    if (chunk == 0 && t == 0) theta_out[b] = s_theta;

    const float theta = s_theta;
    const int row0 = chunk * ROWS_PER_BLOCK;

    const int n0 = row0 + wave;          // rows n0 and n0+4
    const int n1 = n0 + 4;
    const float* arow0 = adj + (size_t)b * N * N + (size_t)n0 * N;
    const float* arow1 = adj + (size_t)b * N * N + (size_t)n1 * N;

    float deg0 = 0.f, e2c0 = 0.f, deg1 = 0.f, e2c1 = 0.f;
    // adj is 268 MB streamed exactly once: nontemporal (L2-bypass) measured
    // faster than cached loads for this stream (428.4 vs 442.0 µs).
    #pragma unroll
    for (int k = 0; k < N / 256; ++k) {               // 16 iterations
        const int i = lane * 4 + k * 256;
        floatx4 a0 = __builtin_nontemporal_load((const floatx4*)&arow0[i]);
        floatx4 a1 = __builtin_nontemporal_load((const floatx4*)&arow1[i]);
        float4 m = *(const float4*)&s_mask[i];
        deg0 += a0.x + a0.y + a0.z + a0.w;
        e2c0 += a0.x * m.x + a0.y * m.y + a0.z * m.z + a0.w * m.w;
        deg1 += a1.x + a1.y + a1.z + a1.w;
        e2c1 += a1.x * m.x + a1.y * m.y + a1.z * m.z + a1.w * m.w;
    }
    // scores = x[b,n,:] . v   (256 floats = 64 lanes x float4)
    float sc0, sc1;
    {
        const float* xrow0 = x + (size_t)b * N * D + (size_t)n0 * D;
        const float* xrow1 = x + (size_t)b * N * D + (size_t)n1 * D;
        float4 xv0 = *(const float4*)&xrow0[lane * 4];
        float4 xv1 = *(const float4*)&xrow1[lane * 4];
        float4 vv  = *(const float4*)&s_v[lane * 4];
        sc0 = xv0.x * vv.x + xv0.y * vv.y + xv0.z * vv.z + xv0.w * vv.w;
        sc1 = xv1.x * vv.x + xv1.y * vv.y + xv1.z * vv.z + xv1.w * vv.w;
    }
    for (int off = 32; off > 0; off >>= 1) {
        deg0 += __shfl_down(deg0, off, 64);
        e2c0 += __shfl_down(e2c0, off, 64);
        sc0  += __shfl_down(sc0,  off, 64);
        deg1 += __shfl_down(deg1, off, 64);
        e2c1 += __shfl_down(e2c1, off, 64);
        sc1  += __shfl_down(sc1,  off, 64);
    }
    if (lane == 0) {
        float d0 = fmaxf(deg0, 1.0f);
        float cand0 = sc0 + ALPHA * (e2c0 / d0);
        float p0 = cand_mask[b * N + n0] / (1.f + expf(-(cand0 - theta)));  // TAU == 1
        p_ws[b * N + n0] = p0;
        float d1 = fmaxf(deg1, 1.0f);
        float cand1 = sc1 + ALPHA * (e2c1 / d1);
        float p1 = cand_mask[b * N + n1] / (1.f + expf(-(cand1 - theta)));
        p_ws[b * N + n1] = p1;
    }
}

// -------------------- kernel 2: top-K_CAP trim + outputs (one block per batch)
// Wave-shfl scans replace the 256-wide Hillis-Steele LDS scans: ~110 -> ~20
// barriers. Radix scan+select runs entirely inside wave 0 (wave-synchronous).
__global__ __launch_bounds__(256) void finalize_kernel(float* p_in, float* out)
{
    const int b = blockIdx.x;
    const int t = threadIdx.x;
    const int wave = t >> 6;
    const int lane = t & 63;
    __shared__ float        sp[N];          // 16 KB
    __shared__ unsigned int hist[256];
    __shared__ unsigned int s_ured[4];
    __shared__ float        s_wred[4];
    __shared__ unsigned int s_bcast[2];

    for (int i = t * 4; i < N; i += 1024)
        *(float4*)&sp[i] = *(const float4*)&p_in[b * N + i];
    __syncthreads();

    // count p > 0.5 (wave shfl reduce + 4 partials)
    {
        unsigned int c = 0;
        for (int i = t; i < N; i += 256) c += (sp[i] > 0.5f) ? 1u : 0u;
        for (int off = 32; off; off >>= 1) c += __shfl_down(c, off, 64);
        if (lane == 0) s_ured[wave] = c;
    }
    __syncthreads();
    const unsigned int over_cnt = s_ured[0] + s_ured[1] + s_ured[2] + s_ured[3];
    const bool need_trim = over_cnt > K_CAP;
    __syncthreads();                        // s_ured reused below

    unsigned int prefix = 0u;       // bit pattern of the K_CAP-th largest value
    unsigned int k_rem = K_CAP;     // becomes #ties-to-keep after last pass
    if (need_trim) {
        for (int pass = 0; pass < 4; ++pass) {
            const int shift = 24 - pass * 8;
            const unsigned int himask = (pass == 0) ? 0u : (0xFFFFFFFFu << (shift + 8));
            hist[t] = 0u;
            __syncthreads();
            for (int i = t; i < N; i += 256) {
                unsigned int u = __float_as_uint(sp[i]);
                if ((u & himask) == prefix)
                    atomicAdd(&hist[(u >> shift) & 255u], 1u);
            }
            __syncthreads();
            // wave 0: suffix-scan 256 bins (4 bins/lane), select the K-th bin.
            if (wave == 0) {
                const unsigned int h0 = hist[lane * 4 + 0];
                const unsigned int h1 = hist[lane * 4 + 1];
                const unsigned int h2 = hist[lane * 4 + 2];
                const unsigned int h3 = hist[lane * 4 + 3];
                const unsigned int s3 = h3, s2 = h2 + s3, s1 = h1 + s2, s0 = h0 + s1;
                unsigned int incl = s0;                 // suffix sum across lanes
                for (int off = 1; off < 64; off <<= 1) {
                    unsigned int o = __shfl_down(incl, off, 64);
                    if (lane + off < 64) incl += o;
                }
                const unsigned int tail = incl - s0;    // sum of lanes > lane
                // bin j: Gincl = tail + s_j, G = Gincl - h_j; select G<k<=Gincl
                const unsigned int gi0 = tail + s0, gi1 = tail + s1,
                                   gi2 = tail + s2, gi3 = tail + s3;
                if (gi0 - h0 < k_rem && k_rem <= gi0) {
                    s_bcast[0] = prefix | ((unsigned int)(lane * 4 + 0) << shift);
                    s_bcast[1] = k_rem - (gi0 - h0);
                }
                if (gi1 - h1 < k_rem && k_rem <= gi1) {
                    s_bcast[0] = prefix | ((unsigned int)(lane * 4 + 1) << shift);
                    s_bcast[1] = k_rem - (gi1 - h1);
                }
                if (gi2 - h2 < k_rem && k_rem <= gi2) {
                    s_bcast[0] = prefix | ((unsigned int)(lane * 4 + 2) << shift);
                    s_bcast[1] = k_rem - (gi2 - h2);
                }
                if (gi3 - h3 < k_rem && k_rem <= gi3) {
                    s_bcast[0] = prefix | ((unsigned int)(lane * 4 + 3) << shift);
                    s_bcast[1] = k_rem - (gi3 - h3);
                }
            }
            __syncthreads();
            prefix = s_bcast[0];
            k_rem  = s_bcast[1];
            __syncthreads();
        }
    }
    const float vk = __uint_as_float(prefix);
    const unsigned int t_keep = k_rem;   // first t_keep ties (by index) are kept

    // exclusive prefix of tie counts over contiguous 16-element chunks
    unsigned int tie_excl = 0;
    if (need_trim) {
        unsigned int local_tie = 0;
        const int base = t * 16;
        for (int j = 0; j < 16; ++j)
            local_tie += (__float_as_uint(sp[base + j]) == prefix) ? 1u : 0u;
        unsigned int incl = local_tie;
        for (int off = 1; off < 64; off <<= 1) {
            unsigned int o = __shfl_up(incl, off, 64);
            if (lane >= off) incl += o;
        }
        if (lane == 63) s_ured[wave] = incl;       // per-wave totals
        __syncthreads();
        unsigned int woff = 0;
        for (int w = 0; w < wave; ++w) woff += s_ured[w];
        tie_excl = woff + incl - local_tie;
    }

    // final: trim, write hard + p, accumulate sum
    float psum = 0.f;
    {
        const int base = t * 16;
        unsigned int tie_rank = tie_excl;
        for (int j = 0; j < 16; ++j) {
            const int i = base + j;
            float p = sp[i];
            if (need_trim) {
                const unsigned int u = __float_as_uint(p);
                bool keep;
                if (u == prefix) { keep = (tie_rank < t_keep); tie_rank++; }
                else             { keep = (p > vk); }
                if (!keep) p = 0.f;
            }
            out[b * N + i]         = (p > 0.5f) ? 1.0f : 0.0f;  // hard gate
            out[B * N + b * N + i] = p;                          // trimmed p
            psum += p;
        }
    }
    for (int off = 32; off; off >>= 1) psum += __shfl_down(psum, off, 64);
    if (lane == 0) s_wred[wave] = psum;
    __syncthreads();
    if (t == 0) {
        const float tot = s_wred[0] + s_wred[1] + s_wred[2] + s_wred[3];
        out[2 * B * N + B + b]     = tot;                        // expected_size
        out[2 * B * N + 2 * B + b] = tot * (1.0f / N);           // mean_p
    }
}

extern "C" void kernel_launch(void* const* d_in, const int* in_sizes, int n_in,
                              void* d_out, int out_size, void* d_ws, size_t ws_size,
                              hipStream_t stream) {
    const float* x            = (const float*)d_in[0];
    const float* adj          = (const float*)d_in[1];
    const float* seed_ctx     = (const float*)d_in[2];
    const float* local_stats  = (const float*)d_in[3];
    const float* cluster_mask = (const float*)d_in[4];
    const float* cand_mask    = (const float*)d_in[5];
    const float* Wq           = (const float*)d_in[6];
    const float* Wk           = (const float*)d_in[7];
    const float* th_w1        = (const float*)d_in[8];
    const float* th_b1        = (const float*)d_in[9];
    const float* th_w2        = (const float*)d_in[10];
    const float* th_b2        = (const float*)d_in[11];
    float* out = (float*)d_out;

    // Scratch aliased onto d_out regions that are fully overwritten later:
    //   p_ws  -> out[BN .. 2BN)   (p region, read-then-rewritten by finalize)
    //   theta -> out[2BN .. 2BN+B) (the actual theta output slot)
    float* p_ws     = out + B * N;
    float* theta_ws = out + 2 * B * N;

    hipLaunchKernelGGL(score_kernel, dim3(B * BLOCKS_PER_BATCH), dim3(256), 0, stream,
                       x, adj, cluster_mask, cand_mask, seed_ctx, local_stats,
                       Wq, Wk, th_w1, th_b1, th_w2, th_b2, p_ws, theta_ws);
    hipLaunchKernelGGL(finalize_kernel, dim3(B), dim3(256), 0, stream,
                       p_ws, out);
}

// Round 4
// 390.440 us; speedup vs baseline: 1.0792x; 1.0792x over previous
//
#include <hip/hip_runtime.h>
#include <math.h>

#define B 4
#define N 4096
#define D 256
#define PROJ 64
#define TH_HIDDEN 128
#define K_CAP 255
#define ALPHA 0.2f
#define ROWS_PER_BLOCK 8                         // 2 rows per wave, interleaved
#define BLOCKS_PER_BATCH (N / ROWS_PER_BLOCK)    // 512

// native vector type for nontemporal builtins (HIP_vector_type is rejected)
typedef float floatx4 __attribute__((ext_vector_type(4)));

// Measured A/B ledger (MI355X, this harness):
//   cached 1-row 446.2 | nt 1-row 437.5 | nt 2-row 428.4 | cached 2-row 442.0 |
//   nt 4-row 433.5 | fused+fences 531.4 | R2 prep-parallel 400.5 (BEST) |
//   R3 prep-fused-into-score 421.4 (REGRESSION: 2048 blocks x ~380 KB redundant
//   weight reads = ~780 MB extra L2 traffic ~ +21 us. Weight-reading prep must
//   stay a small separate dispatch.)
// ~320 us of dur_us is harness poison-fills (2x160 us 1-GiB fillBuffer inside
// the timed region) — uncontrollable.
// R4: revert to R2 score; keep R3 wave-scan finalize; prep rewritten with
//     float4 weight loads + deeper split-K (theta MLP 12us->~3us predicted)
//     and Wk register prefetch hidden under argmax.

// -------------------- kernel 1: seed argmax, v = Wk*(Wq^T x_seed)/8, theta MLP
// Grid = 2*B. Blocks [0,B): argmax + v. Blocks [B,2B): theta MLP.
__global__ __launch_bounds__(256) void prep_kernel(
    const float* __restrict__ x, const float* __restrict__ cluster_mask,
    const float* __restrict__ seed_ctx, const float* __restrict__ local_stats,
    const float* __restrict__ Wq, const float* __restrict__ Wk,
    const float* __restrict__ th_w1, const float* __restrict__ th_b1,
    const float* __restrict__ th_w2, const float* __restrict__ th_b2,
    float* v_ws, float* theta_out)
{
    const int bb = blockIdx.x;
    const int t = threadIdx.x;

    if (bb >= B) {
        // ---------------- theta MLP block ----------------
        // h[j] = relu(sum_i in[i]*w1[i*128+j] + b1[j]); theta = h@w2 + b2
        // Layout: 32 neuron-quads (float4 of j) x 8 K-slices (64 rows each).
        const int b = bb - B;
        __shared__ float  s_in[512];        // [seed_ctx(384), local_stats(128)]
        __shared__ float4 s_p4[8][32];      // [kslice][quad] partials
        __shared__ float  s_h[TH_HIDDEN];

        if (t < 96)       ((float4*)s_in)[t]      = ((const float4*)(seed_ctx + b * 384))[t];
        else if (t < 128) ((float4*)s_in)[t]      = ((const float4*)(local_stats + b * 128))[t - 96];
        __syncthreads();

        {
            const int g = t & 31;          // neurons 4g..4g+3
            const int k = t >> 5;          // rows 64k..64k+63
            const float* w1 = th_w1 + (size_t)(k * 64) * TH_HIDDEN + 4 * g;
            const float* xin = s_in + k * 64;
            float4 a = {0.f, 0.f, 0.f, 0.f};
            #pragma unroll 8
            for (int i = 0; i < 64; ++i) {
                const float xv = xin[i];
                const float4 w = *(const float4*)(w1 + (size_t)i * TH_HIDDEN);
                a.x += xv * w.x; a.y += xv * w.y; a.z += xv * w.z; a.w += xv * w.w;
            }
            s_p4[k][g] = a;
        }
        __syncthreads();
        if (t < 32) {
            float4 s = s_p4[0][t];
            #pragma unroll
            for (int kk = 1; kk < 8; ++kk) {
                const float4 q = s_p4[kk][t];
                s.x += q.x; s.y += q.y; s.z += q.z; s.w += q.w;
            }
            const float4 b1 = *(const float4*)(th_b1 + 4 * t);
            s_h[4 * t + 0] = fmaxf(s.x + b1.x, 0.f);
            s_h[4 * t + 1] = fmaxf(s.y + b1.y, 0.f);
            s_h[4 * t + 2] = fmaxf(s.z + b1.z, 0.f);
            s_h[4 * t + 3] = fmaxf(s.w + b1.w, 0.f);
        }
        __syncthreads();
        if (t < 64) {
            float a2 = s_h[t] * th_w2[t] + s_h[t + 64] * th_w2[t + 64];
            for (int off = 32; off; off >>= 1) a2 += __shfl_down(a2, off, 64);
            if (t == 0) theta_out[b] = a2 + th_b2[0];
        }
        return;
    }

    // ---------------- argmax + v block ----------------
    const int b = bb;
    __shared__ float  s_red[256];
    __shared__ int    s_idx[256];
    __shared__ float  s_xseed[D];
    __shared__ float4 s_q4[16][16];
    __shared__ float  s_r[PROJ];

    // prefetch this thread's Wk row (64 floats) into VGPRs; cold-HBM latency
    // hides under the argmax phase below.
    float4 wk[16];
    {
        const float4* wkp = (const float4*)(Wk + (size_t)t * PROJ);
        #pragma unroll
        for (int j = 0; j < 16; ++j) wk[j] = wkp[j];
    }

    // argmax (first occurrence of max, matching np.argmax)
    float bestv = -1e30f; int besti = 0;
    for (int i = t; i < N; i += 256) {
        float vv = cluster_mask[b * N + i];
        if (vv > bestv) { bestv = vv; besti = i; }  // strict > keeps lowest index
    }
    s_red[t] = bestv; s_idx[t] = besti;
    __syncthreads();
    for (int s = 128; s > 0; s >>= 1) {
        if (t < s) {
            float v2 = s_red[t + s]; int i2 = s_idx[t + s];
            if (v2 > s_red[t] || (v2 == s_red[t] && i2 < s_idx[t])) {
                s_red[t] = v2; s_idx[t] = i2;
            }
        }
        __syncthreads();
    }
    const int seed = s_idx[0];

    // stage x[b, seed, :]
    s_xseed[t] = x[(size_t)b * N * D + (size_t)seed * D + t];
    __syncthreads();

    // r[j] = sum_d x_seed[d] * Wq[d*64+j]
    // Layout: 16 output-quads (float4 of j) x 16 K-slices (16 rows each).
    {
        const int g = t & 15;          // outputs 4g..4g+3
        const int k = t >> 4;          // rows 16k..16k+15
        const float* wq = Wq + (size_t)(k * 16) * PROJ + 4 * g;
        const float* xs = s_xseed + k * 16;
        float4 a = {0.f, 0.f, 0.f, 0.f};
        #pragma unroll
        for (int i = 0; i < 16; ++i) {
            const float xv = xs[i];
            const float4 w = *(const float4*)(wq + (size_t)i * PROJ);
            a.x += xv * w.x; a.y += xv * w.y; a.z += xv * w.z; a.w += xv * w.w;
        }
        s_q4[k][g] = a;
    }
    __syncthreads();
    if (t < 16) {
        float4 s = s_q4[0][t];
        #pragma unroll
        for (int kk = 1; kk < 16; ++kk) {
            const float4 q = s_q4[kk][t];
            s.x += q.x; s.y += q.y; s.z += q.z; s.w += q.w;
        }
        *(float4*)&s_r[4 * t] = s;
    }
    __syncthreads();

    // v[t] = (Wk[t,:] . r) / sqrt(PROJ)   (Wk row already in VGPRs)
    {
        float acc = 0.f;
        #pragma unroll
        for (int j4 = 0; j4 < PROJ / 4; ++j4) {
            const float4 w = wk[j4];
            const float4 r4 = *(const float4*)&s_r[j4 * 4];
            acc += w.x * r4.x + w.y * r4.y + w.z * r4.z + w.w * r4.w;
        }
        v_ws[b * D + t] = acc * 0.125f;
    }
}

// -------------------- kernel 2: streaming adj pass -> deg, e2c, score -> p
// Byte-identical hot loop to the measured-best 400.5 config (nt 2-row).
__global__ __launch_bounds__(256) void score_kernel(
    const float* __restrict__ x, const float* __restrict__ adj,
    const float* __restrict__ cluster_mask, const float* __restrict__ cand_mask,
    const float* __restrict__ v_ws, const float* __restrict__ theta_ws,
    float* __restrict__ p_ws)
{
    const int b = blockIdx.x / BLOCKS_PER_BATCH;
    const int chunk = blockIdx.x % BLOCKS_PER_BATCH;
    const int t = threadIdx.x;
    const int wave = t >> 6;
    const int lane = t & 63;

    __shared__ float s_mask[N];   // 16 KB
    __shared__ float s_v[D];

    for (int i = t * 4; i < N; i += 1024)
        *(float4*)&s_mask[i] = *(const float4*)&cluster_mask[b * N + i];
    if (t < D) s_v[t] = v_ws[b * D + t];
    __syncthreads();

    const float theta = theta_ws[b];
    const int row0 = chunk * ROWS_PER_BLOCK;

    const int n0 = row0 + wave;          // rows n0 and n0+4
    const int n1 = n0 + 4;
    const float* arow0 = adj + (size_t)b * N * N + (size_t)n0 * N;
    const float* arow1 = adj + (size_t)b * N * N + (size_t)n1 * N;

    float deg0 = 0.f, e2c0 = 0.f, deg1 = 0.f, e2c1 = 0.f;
    // adj is 268 MB streamed exactly once: nontemporal (L2-bypass) measured
    // faster than cached loads for this stream (428.4 vs 442.0 µs).
    #pragma unroll
    for (int k = 0; k < N / 256; ++k) {               // 16 iterations
        const int i = lane * 4 + k * 256;
        floatx4 a0 = __builtin_nontemporal_load((const floatx4*)&arow0[i]);
        floatx4 a1 = __builtin_nontemporal_load((const floatx4*)&arow1[i]);
        float4 m = *(const float4*)&s_mask[i];
        deg0 += a0.x + a0.y + a0.z + a0.w;
        e2c0 += a0.x * m.x + a0.y * m.y + a0.z * m.z + a0.w * m.w;
        deg1 += a1.x + a1.y + a1.z + a1.w;
        e2c1 += a1.x * m.x + a1.y * m.y + a1.z * m.z + a1.w * m.w;
    }
    // scores = x[b,n,:] . v   (256 floats = 64 lanes x float4)
    float sc0, sc1;
    {
        const float* xrow0 = x + (size_t)b * N * D + (size_t)n0 * D;
        const float* xrow1 = x + (size_t)b * N * D + (size_t)n1 * D;
        float4 xv0 = *(const float4*)&xrow0[lane * 4];
        float4 xv1 = *(const float4*)&xrow1[lane * 4];
        float4 vv  = *(const float4*)&s_v[lane * 4];
        sc0 = xv0.x * vv.x + xv0.y * vv.y + xv0.z * vv.z + xv0.w * vv.w;
        sc1 = xv1.x * vv.x + xv1.y * vv.y + xv1.z * vv.z + xv1.w * vv.w;
    }
    for (int off = 32; off > 0; off >>= 1) {
        deg0 += __shfl_down(deg0, off, 64);
        e2c0 += __shfl_down(e2c0, off, 64);
        sc0  += __shfl_down(sc0,  off, 64);
        deg1 += __shfl_down(deg1, off, 64);
        e2c1 += __shfl_down(e2c1, off, 64);
        sc1  += __shfl_down(sc1,  off, 64);
    }
    if (lane == 0) {
        float d0 = fmaxf(deg0, 1.0f);
        float cand0 = sc0 + ALPHA * (e2c0 / d0);
        float p0 = cand_mask[b * N + n0] / (1.f + expf(-(cand0 - theta)));  // TAU == 1
        p_ws[b * N + n0] = p0;
        float d1 = fmaxf(deg1, 1.0f);
        float cand1 = sc1 + ALPHA * (e2c1 / d1);
        float p1 = cand_mask[b * N + n1] / (1.f + expf(-(cand1 - theta)));
        p_ws[b * N + n1] = p1;
    }
}

// -------------------- kernel 3: top-K_CAP trim + outputs (one block per batch)
// Wave-shfl scans replace the 256-wide Hillis-Steele LDS scans: ~110 -> ~20
// barriers. Radix scan+select runs entirely inside wave 0 (wave-synchronous).
__global__ __launch_bounds__(256) void finalize_kernel(float* p_in, float* out)
{
    const int b = blockIdx.x;
    const int t = threadIdx.x;
    const int wave = t >> 6;
    const int lane = t & 63;
    __shared__ float        sp[N];          // 16 KB
    __shared__ unsigned int hist[256];
    __shared__ unsigned int s_ured[4];
    __shared__ float        s_wred[4];
    __shared__ unsigned int s_bcast[2];

    for (int i = t * 4; i < N; i += 1024)
        *(float4*)&sp[i] = *(const float4*)&p_in[b * N + i];
    __syncthreads();

    // count p > 0.5 (wave shfl reduce + 4 partials)
    {
        unsigned int c = 0;
        for (int i = t; i < N; i += 256) c += (sp[i] > 0.5f) ? 1u : 0u;
        for (int off = 32; off; off >>= 1) c += __shfl_down(c, off, 64);
        if (lane == 0) s_ured[wave] = c;
    }
    __syncthreads();
    const unsigned int over_cnt = s_ured[0] + s_ured[1] + s_ured[2] + s_ured[3];
    const bool need_trim = over_cnt > K_CAP;
    __syncthreads();                        // s_ured reused below

    unsigned int prefix = 0u;       // bit pattern of the K_CAP-th largest value
    unsigned int k_rem = K_CAP;     // becomes #ties-to-keep after last pass
    if (need_trim) {
        for (int pass = 0; pass < 4; ++pass) {
            const int shift = 24 - pass * 8;
            const unsigned int himask = (pass == 0) ? 0u : (0xFFFFFFFFu << (shift + 8));
            hist[t] = 0u;
            __syncthreads();
            for (int i = t; i < N; i += 256) {
                unsigned int u = __float_as_uint(sp[i]);
                if ((u & himask) == prefix)
                    atomicAdd(&hist[(u >> shift) & 255u], 1u);
            }
            __syncthreads();
            // wave 0: suffix-scan 256 bins (4 bins/lane), select the K-th bin.
            if (wave == 0) {
                const unsigned int h0 = hist[lane * 4 + 0];
                const unsigned int h1 = hist[lane * 4 + 1];
                const unsigned int h2 = hist[lane * 4 + 2];
                const unsigned int h3 = hist[lane * 4 + 3];
                const unsigned int s3 = h3, s2 = h2 + s3, s1 = h1 + s2, s0 = h0 + s1;
                unsigned int incl = s0;                 // suffix sum across lanes
                for (int off = 1; off < 64; off <<= 1) {
                    unsigned int o = __shfl_down(incl, off, 64);
                    if (lane + off < 64) incl += o;
                }
                const unsigned int tail = incl - s0;    // sum of lanes > lane
                // bin j: Gincl = tail + s_j, G = Gincl - h_j; select G<k<=Gincl
                const unsigned int gi0 = tail + s0, gi1 = tail + s1,
                                   gi2 = tail + s2, gi3 = tail + s3;
                if (gi0 - h0 < k_rem && k_rem <= gi0) {
                    s_bcast[0] = prefix | ((unsigned int)(lane * 4 + 0) << shift);
                    s_bcast[1] = k_rem - (gi0 - h0);
                }
                if (gi1 - h1 < k_rem && k_rem <= gi1) {
                    s_bcast[0] = prefix | ((unsigned int)(lane * 4 + 1) << shift);
                    s_bcast[1] = k_rem - (gi1 - h1);
                }
                if (gi2 - h2 < k_rem && k_rem <= gi2) {
                    s_bcast[0] = prefix | ((unsigned int)(lane * 4 + 2) << shift);
                    s_bcast[1] = k_rem - (gi2 - h2);
                }
                if (gi3 - h3 < k_rem && k_rem <= gi3) {
                    s_bcast[0] = prefix | ((unsigned int)(lane * 4 + 3) << shift);
                    s_bcast[1] = k_rem - (gi3 - h3);
                }
            }
            __syncthreads();
            prefix = s_bcast[0];
            k_rem  = s_bcast[1];
            __syncthreads();
        }
    }
    const float vk = __uint_as_float(prefix);
    const unsigned int t_keep = k_rem;   // first t_keep ties (by index) are kept

    // exclusive prefix of tie counts over contiguous 16-element chunks
    unsigned int tie_excl = 0;
    if (need_trim) {
        unsigned int local_tie = 0;
        const int base = t * 16;
        for (int j = 0; j < 16; ++j)
            local_tie += (__float_as_uint(sp[base + j]) == prefix) ? 1u : 0u;
        unsigned int incl = local_tie;
        for (int off = 1; off < 64; off <<= 1) {
            unsigned int o = __shfl_up(incl, off, 64);
            if (lane >= off) incl += o;
        }
        if (lane == 63) s_ured[wave] = incl;       // per-wave totals
        __syncthreads();
        unsigned int woff = 0;
        for (int w = 0; w < wave; ++w) woff += s_ured[w];
        tie_excl = woff + incl - local_tie;
    }

    // final: trim, write hard + p, accumulate sum
    float psum = 0.f;
    {
        const int base = t * 16;
        unsigned int tie_rank = tie_excl;
        for (int j = 0; j < 16; ++j) {
            const int i = base + j;
            float p = sp[i];
            if (need_trim) {
                const unsigned int u = __float_as_uint(p);
                bool keep;
                if (u == prefix) { keep = (tie_rank < t_keep); tie_rank++; }
                else             { keep = (p > vk); }
                if (!keep) p = 0.f;
            }
            out[b * N + i]         = (p > 0.5f) ? 1.0f : 0.0f;  // hard gate
            out[B * N + b * N + i] = p;                          // trimmed p
            psum += p;
        }
    }
    for (int off = 32; off; off >>= 1) psum += __shfl_down(psum, off, 64);
    if (lane == 0) s_wred[wave] = psum;
    __syncthreads();
    if (t == 0) {
        const float tot = s_wred[0] + s_wred[1] + s_wred[2] + s_wred[3];
        out[2 * B * N + B + b]     = tot;                        // expected_size
        out[2 * B * N + 2 * B + b] = tot * (1.0f / N);           // mean_p
    }
}

extern "C" void kernel_launch(void* const* d_in, const int* in_sizes, int n_in,
                              void* d_out, int out_size, void* d_ws, size_t ws_size,
                              hipStream_t stream) {
    const float* x            = (const float*)d_in[0];
    const float* adj          = (const float*)d_in[1];
    const float* seed_ctx     = (const float*)d_in[2];
    const float* local_stats  = (const float*)d_in[3];
    const float* cluster_mask = (const float*)d_in[4];
    const float* cand_mask    = (const float*)d_in[5];
    const float* Wq           = (const float*)d_in[6];
    const float* Wk           = (const float*)d_in[7];
    const float* th_w1        = (const float*)d_in[8];
    const float* th_b1        = (const float*)d_in[9];
    const float* th_w2        = (const float*)d_in[10];
    const float* th_b2        = (const float*)d_in[11];
    float* out = (float*)d_out;

    // Scratch aliased onto d_out regions that are fully overwritten later:
    //   v_ws   -> out[0 .. B*D)          (hard region, rewritten by finalize)
    //   theta  -> out[2BN .. 2BN+B)      (the actual theta output slot)
    //   p_ws   -> out[BN .. 2BN)         (p region, read-then-rewritten by finalize)
    float* v_ws     = out;
    float* p_ws     = out + B * N;
    float* theta_ws = out + 2 * B * N;

    hipLaunchKernelGGL(prep_kernel, dim3(2 * B), dim3(256), 0, stream,
                       x, cluster_mask, seed_ctx, local_stats, Wq, Wk,
                       th_w1, th_b1, th_w2, th_b2, v_ws, theta_ws);
    hipLaunchKernelGGL(score_kernel, dim3(B * BLOCKS_PER_BATCH), dim3(256), 0, stream,
                       x, adj, cluster_mask, cand_mask, v_ws, theta_ws, p_ws);
    hipLaunchKernelGGL(finalize_kernel, dim3(B), dim3(256), 0, stream,
                       p_ws, out);
}